// Round 1
// baseline (703.858 us; speedup 1.0000x reference)
//
#include <hip/hip_runtime.h>
#include <hip/hip_bf16.h>

#define NN    65536
#define KDIM  1024
#define HDIM  256
#define NC    8
#define BM    64
#define BK    32
#define LSTR  40   // BK + 8 pad (keeps 16B alignment for b128: 40*2=80 bytes/row)

typedef __bf16 bf16x8 __attribute__((ext_vector_type(8)));
typedef float  f32x4  __attribute__((ext_vector_type(4)));

static __device__ __forceinline__ unsigned short f2bf_rne(float f) {
    unsigned int u = __float_as_uint(f);
    unsigned int r = u + 0x7fffu + ((u >> 16) & 1u);
    return (unsigned short)(r >> 16);
}

// ---------------- Kernel 1: bf16-MFMA GEMM + ReLU + per-cluster segment sum ----
__global__ __launch_bounds__(256, 2) void gemm_relu_segsum(
    const float* __restrict__ x, const int* __restrict__ cid,
    const float* __restrict__ W1, const float* __restrict__ b1,
    float* __restrict__ gsums)
{
    __shared__ unsigned short xs[BM * LSTR];     // 5120 B
    __shared__ unsigned short wsT[HDIM * LSTR];  // 20480 B
    __shared__ float lsums[NC * HDIM];           // 8192 B
    __shared__ int cids[BM];

    const int tid  = threadIdx.x;
    const int wave = tid >> 6;
    const int lane = tid & 63;
    const int l15  = lane & 15;
    const int q    = lane >> 4;   // 0..3
    const int kq   = q * 8;       // k offset within BK
    const int row0 = blockIdx.x * BM;

    for (int i = tid; i < NC * HDIM; i += 256) lsums[i] = 0.0f;
    if (tid < BM) cids[tid] = cid[row0 + tid];

    f32x4 acc[4][4];
    #pragma unroll
    for (int i = 0; i < 4; ++i)
        #pragma unroll
        for (int j = 0; j < 4; ++j)
            #pragma unroll
            for (int r = 0; r < 4; ++r) acc[i][j][r] = 0.0f;

    for (int kb = 0; kb < KDIM; kb += BK) {
        __syncthreads();
        // stage x tile: 64 rows x 32 k (2 float4 per thread)
        #pragma unroll
        for (int p = 0; p < 2; ++p) {
            int idx = p * 256 + tid;
            int r = idx >> 3, c4 = idx & 7;
            const float4 v = *(const float4*)(x + (size_t)(row0 + r) * KDIM + kb + c4 * 4);
            unsigned long long pk =
                  (unsigned long long)f2bf_rne(v.x)
                | ((unsigned long long)f2bf_rne(v.y) << 16)
                | ((unsigned long long)f2bf_rne(v.z) << 32)
                | ((unsigned long long)f2bf_rne(v.w) << 48);
            *(unsigned long long*)&xs[r * LSTR + c4 * 4] = pk;
        }
        // stage W1 tile: 256 rows x 32 k (8 float4 per thread)
        #pragma unroll
        for (int p = 0; p < 8; ++p) {
            int idx = p * 256 + tid;
            int r = idx >> 3, c4 = idx & 7;
            const float4 v = *(const float4*)(W1 + (size_t)r * KDIM + kb + c4 * 4);
            unsigned long long pk =
                  (unsigned long long)f2bf_rne(v.x)
                | ((unsigned long long)f2bf_rne(v.y) << 16)
                | ((unsigned long long)f2bf_rne(v.z) << 32)
                | ((unsigned long long)f2bf_rne(v.w) << 48);
            *(unsigned long long*)&wsT[r * LSTR + c4 * 4] = pk;
        }
        __syncthreads();

        bf16x8 af[4], bfr[4];
        #pragma unroll
        for (int i = 0; i < 4; ++i)
            af[i] = *(const bf16x8*)&xs[(i * 16 + l15) * LSTR + kq];
        #pragma unroll
        for (int j = 0; j < 4; ++j)
            bfr[j] = *(const bf16x8*)&wsT[(wave * 64 + j * 16 + l15) * LSTR + kq];

        #pragma unroll
        for (int i = 0; i < 4; ++i)
            #pragma unroll
            for (int j = 0; j < 4; ++j)
                acc[i][j] = __builtin_amdgcn_mfma_f32_16x16x32_bf16(af[i], bfr[j], acc[i][j], 0, 0, 0);
    }

    // epilogue: bias + relu + per-cluster LDS accumulation
    float b1v[4];
    #pragma unroll
    for (int j = 0; j < 4; ++j) b1v[j] = b1[wave * 64 + j * 16 + l15];

    #pragma unroll
    for (int i = 0; i < 4; ++i) {
        #pragma unroll
        for (int j = 0; j < 4; ++j) {
            const int col = wave * 64 + j * 16 + l15;
            #pragma unroll
            for (int r = 0; r < 4; ++r) {
                float v = fmaxf(acc[i][j][r] + b1v[j], 0.0f);
                int m = i * 16 + q * 4 + r;       // local row (C/D: row=(lane>>4)*4+reg)
                int k = cids[m];
                atomicAdd(&lsums[k * HDIM + col], v);
            }
        }
    }
    __syncthreads();
    // thread tid owns column tid: 8 global atomics per thread
    #pragma unroll
    for (int k = 0; k < NC; ++k)
        atomicAdd(&gsums[k * HDIM + tid], lsums[k * HDIM + tid]);
}

// ---------------- Kernel 0: cluster counts --------------------------------
__global__ void count_kernel(const int* __restrict__ cid, int* __restrict__ counts)
{
    __shared__ int h[NC];
    if (threadIdx.x < NC) h[threadIdx.x] = 0;
    __syncthreads();
    int i = blockIdx.x * blockDim.x + threadIdx.x;
    int stride = gridDim.x * blockDim.x;
    for (; i < NN; i += stride) atomicAdd(&h[cid[i]], 1);
    __syncthreads();
    if (threadIdx.x < NC) atomicAdd(&counts[threadIdx.x], h[threadIdx.x]);
}

// ---------------- Kernel 2: h_cluster -> h_path (Linear+ReLU) -------------
__global__ __launch_bounds__(256) void cluster_mlp(
    const float* __restrict__ gsums, const int* __restrict__ counts,
    const float* __restrict__ Wf, const float* __restrict__ bfv,
    float* __restrict__ h_path)
{
    __shared__ float hc[HDIM];
    const int k = blockIdx.x, c = threadIdx.x;
    float cnt = fmaxf((float)counts[k], 1.0f);
    hc[c] = gsums[k * HDIM + c] / cnt;
    __syncthreads();
    const float4* w4 = (const float4*)(Wf + (size_t)c * HDIM);
    float a0 = 0.f, a1 = 0.f, a2 = 0.f, a3 = 0.f;
    #pragma unroll
    for (int t = 0; t < 16; ++t) {
        const int d = t * 16;
        float4 w0 = w4[t * 4 + 0], w1 = w4[t * 4 + 1], w2 = w4[t * 4 + 2], w3 = w4[t * 4 + 3];
        a0 += w0.x * hc[d + 0]  + w0.y * hc[d + 1]  + w0.z * hc[d + 2]  + w0.w * hc[d + 3];
        a1 += w1.x * hc[d + 4]  + w1.y * hc[d + 5]  + w1.z * hc[d + 6]  + w1.w * hc[d + 7];
        a2 += w2.x * hc[d + 8]  + w2.y * hc[d + 9]  + w2.z * hc[d + 10] + w2.w * hc[d + 11];
        a3 += w3.x * hc[d + 12] + w3.y * hc[d + 13] + w3.z * hc[d + 14] + w3.w * hc[d + 15];
    }
    float s = (a0 + a1) + (a2 + a3) + bfv[c];
    h_path[k * HDIM + c] = fmaxf(s, 0.0f);
}

// ---------------- Kernel 3: gated attention logits ------------------------
__global__ __launch_bounds__(256) void attn_logits(
    const float* __restrict__ h_path,
    const float* __restrict__ Wa, const float* __restrict__ ba,
    const float* __restrict__ Wb, const float* __restrict__ bb,
    const float* __restrict__ Wc, const float* __restrict__ bc,
    float* __restrict__ logits)
{
    __shared__ float hp[HDIM];
    __shared__ float part[4];
    const int k = blockIdx.x, c = threadIdx.x;
    hp[c] = h_path[k * HDIM + c];
    __syncthreads();
    const float4* wa4 = (const float4*)(Wa + (size_t)c * HDIM);
    const float4* wb4 = (const float4*)(Wb + (size_t)c * HDIM);
    float za = 0.f, zb = 0.f;
    #pragma unroll 8
    for (int t = 0; t < 64; ++t) {
        float4 wa = wa4[t], wb = wb4[t];
        const int d = t * 4;
        za += wa.x * hp[d] + wa.y * hp[d + 1] + wa.z * hp[d + 2] + wa.w * hp[d + 3];
        zb += wb.x * hp[d] + wb.y * hp[d + 1] + wb.z * hp[d + 2] + wb.w * hp[d + 3];
    }
    float a = tanhf(za + ba[c]);
    float g = 1.0f / (1.0f + expf(-(zb + bb[c])));
    float v = a * g * Wc[c];
    #pragma unroll
    for (int off = 32; off > 0; off >>= 1) v += __shfl_down(v, off, 64);
    if ((threadIdx.x & 63) == 0) part[threadIdx.x >> 6] = v;
    __syncthreads();
    if (threadIdx.x == 0) logits[k] = part[0] + part[1] + part[2] + part[3] + bc[0];
}

// ---------------- Kernel 4: softmax over clusters + weighted sum ----------
__global__ __launch_bounds__(256) void attn_final(
    const float* __restrict__ logits, const float* __restrict__ h_path,
    float* __restrict__ out)
{
    const int c = threadIdx.x;
    float lg[NC];
    float m = -1e30f;
    #pragma unroll
    for (int k = 0; k < NC; ++k) { lg[k] = logits[k]; m = fmaxf(m, lg[k]); }
    float s = 0.f;
    #pragma unroll
    for (int k = 0; k < NC; ++k) { lg[k] = expf(lg[k] - m); s += lg[k]; }
    float inv = 1.0f / s;
    float acc = 0.f;
    #pragma unroll
    for (int k = 0; k < NC; ++k) acc += lg[k] * inv * h_path[k * HDIM + c];
    out[c] = acc;
}

extern "C" void kernel_launch(void* const* d_in, const int* in_sizes, int n_in,
                              void* d_out, int out_size, void* d_ws, size_t ws_size,
                              hipStream_t stream)
{
    (void)in_sizes; (void)n_in; (void)out_size; (void)ws_size;
    const float* x   = (const float*)d_in[0];
    const int*   cid = (const int*)  d_in[1];
    const float* W1  = (const float*)d_in[2];
    const float* b1  = (const float*)d_in[3];
    const float* Wf  = (const float*)d_in[4];
    const float* bfv = (const float*)d_in[5];
    const float* Wa  = (const float*)d_in[6];
    const float* ba  = (const float*)d_in[7];
    const float* Wb  = (const float*)d_in[8];
    const float* bb  = (const float*)d_in[9];
    const float* Wc  = (const float*)d_in[10];
    const float* bc  = (const float*)d_in[11];
    float* out = (float*)d_out;

    float* wsf    = (float*)d_ws;
    float* gsums  = wsf;                    // 2048 floats
    int*   counts = (int*)(wsf + 2048);     // 8
    float* logits = wsf + 2056;             // 8
    float* h_path = wsf + 2064;             // 2048

    // zero gsums + counts + logits (ws is poisoned 0xAA before every launch)
    hipMemsetAsync(d_ws, 0, (size_t)(2048 + 16) * sizeof(float), stream);

    hipLaunchKernelGGL(count_kernel,     dim3(64),       dim3(256), 0, stream, cid, counts);
    hipLaunchKernelGGL(gemm_relu_segsum, dim3(NN / BM),  dim3(256), 0, stream, x, cid, W1, b1, gsums);
    hipLaunchKernelGGL(cluster_mlp,      dim3(NC),       dim3(256), 0, stream, gsums, counts, Wf, bfv, h_path);
    hipLaunchKernelGGL(attn_logits,      dim3(NC),       dim3(256), 0, stream, h_path, Wa, ba, Wb, bb, Wc, bc, logits);
    hipLaunchKernelGGL(attn_final,       dim3(1),        dim3(256), 0, stream, logits, h_path, out);
}

// Round 2
// 655.796 us; speedup vs baseline: 1.0733x; 1.0733x over previous
//
#include <hip/hip_runtime.h>
#include <hip/hip_bf16.h>

#define NN    65536
#define KDIM  1024
#define HDIM  256
#define NC    8
#define BM    64
#define NKB   16      // number of 64-wide K blocks

typedef __bf16 bf16x8 __attribute__((ext_vector_type(8)));
typedef float  f32x4  __attribute__((ext_vector_type(4)));
typedef __attribute__((address_space(1))) void GV;
typedef __attribute__((address_space(3))) void LV;

static __device__ __forceinline__ void async_cp16(const void* g, void* l) {
    __builtin_amdgcn_global_load_lds((GV*)g, (LV*)l, 16, 0, 0);
}

static __device__ __forceinline__ unsigned short f2bf_rne(float f) {
    unsigned int u = __float_as_uint(f);
    unsigned int r = u + 0x7fffu + ((u >> 16) & 1u);
    return (unsigned short)(r >> 16);
}

static __device__ __forceinline__ unsigned long long pack4bf(float4 v) {
    return (unsigned long long)f2bf_rne(v.x)
         | ((unsigned long long)f2bf_rne(v.y) << 16)
         | ((unsigned long long)f2bf_rne(v.z) << 32)
         | ((unsigned long long)f2bf_rne(v.w) << 48);
}

// ---- Kernel 1: W1 fp32 -> bf16 in gemm-tile order, + cluster counts ------
// W1b flat chunk index: kbi*2048 + h*1024 + n*4 + kc  (chunk = 8 bf16 = 16 B)
// holds W1[n][kbi*64 + h*32 + kc*8 .. +7]
__global__ __launch_bounds__(256) void prep_kernel(
    const float* __restrict__ W1, unsigned short* __restrict__ W1b,
    const int* __restrict__ cid, int* __restrict__ counts)
{
    __shared__ int hcnt[NC];
    if (threadIdx.x < NC) hcnt[threadIdx.x] = 0;
    __syncthreads();

    const int gid = blockIdx.x * 256 + threadIdx.x;   // 0..32767
    const int kc  = gid & 3;
    const int n   = (gid >> 2) & 255;
    const int h   = (gid >> 10) & 1;
    const int kbi = gid >> 11;
    const float* src = W1 + (size_t)n * KDIM + kbi * 64 + h * 32 + kc * 8;
    float4 v0 = *(const float4*)(src);
    float4 v1 = *(const float4*)(src + 4);
    ulonglong2 pk;
    pk.x = pack4bf(v0);
    pk.y = pack4bf(v1);
    *(ulonglong2*)(W1b + (size_t)gid * 8) = pk;

    atomicAdd(&hcnt[cid[gid]], 1);
    atomicAdd(&hcnt[cid[gid + 32768]], 1);
    __syncthreads();
    if (threadIdx.x < NC) atomicAdd(&counts[threadIdx.x], hcnt[threadIdx.x]);
}

// ---- Kernel 2: bf16 MFMA GEMM + ReLU + per-cluster segment sum -----------
__global__ __launch_bounds__(256, 3) void gemm_kernel(
    const float* __restrict__ x, const int* __restrict__ cid,
    const unsigned short* __restrict__ W1b, const float* __restrict__ b1,
    float* __restrict__ gsums)
{
    __shared__ __align__(16) unsigned short xs[2][BM * 32];     // 8 KB  (2 k-halves, 64B rows)
    __shared__ __align__(16) unsigned short wsb[2][HDIM * 32];  // 32 KB (chunk-linear for async cp)
    __shared__ float lsums[HDIM * NC];                          // 8 KB, [col][k]
    __shared__ int cids[BM];

    const int tid  = threadIdx.x;
    const int wave = tid >> 6;
    const int lane = tid & 63;
    const int l15  = lane & 15;
    const int q    = lane >> 4;
    const int row0 = blockIdx.x * BM;

    for (int i = tid; i < HDIM * NC; i += 256) lsums[i] = 0.0f;
    if (tid < BM) cids[tid] = cid[row0 + tid];

    f32x4 acc[4][4];
    #pragma unroll
    for (int i = 0; i < 4; ++i)
        #pragma unroll
        for (int j = 0; j < 4; ++j)
            #pragma unroll
            for (int r = 0; r < 4; ++r) acc[i][j][r] = 0.0f;

    // async W1 staging: this wave covers chunks [wave*512, wave*512+512)
    const unsigned short* wg0 = W1b + ((size_t)(wave * 512 + lane)) * 8;
    unsigned short* wl0 = &wsb[0][0] + wave * 4096;   // wave*512 chunks * 8 elems

    const float* xg0 = x + (size_t)row0 * KDIM;

    for (int kbi = 0; kbi < NKB; ++kbi) {
        __syncthreads();

        // W1 tile: 2048 chunks, async, perfectly coalesced, lane-linear in LDS
        const unsigned short* wg = wg0 + (size_t)kbi * 16384;
        #pragma unroll
        for (int t = 0; t < 8; ++t)
            async_cp16(wg + t * 512, wl0 + t * 512);

        // x tile: 64 rows x 64 k fp32, convert to bf16 into 2 k-half buffers
        const float* xg = xg0 + kbi * 64;
        #pragma unroll
        for (int p = 0; p < 4; ++p) {
            int idx = p * 256 + tid;
            int r = idx >> 4, c = idx & 15;            // c = float4 chunk in row
            float4 v = *(const float4*)(xg + (size_t)r * KDIM + c * 4);
            unsigned long long pk = pack4bf(v);
            *(unsigned long long*)&xs[c >> 3][r * 32 + (c & 7) * 4] = pk;
        }
        __syncthreads();   // drains vmcnt(0): both async W1 and x ds_writes

        #pragma unroll
        for (int s = 0; s < 2; ++s) {
            bf16x8 af[4], bfr[4];
            #pragma unroll
            for (int i = 0; i < 4; ++i)
                af[i] = *(const bf16x8*)&xs[s][(i * 16 + l15) * 32 + q * 8];
            #pragma unroll
            for (int j = 0; j < 4; ++j)
                bfr[j] = *(const bf16x8*)&wsb[s][(wave * 64 + j * 16 + l15) * 32 + q * 8];
            #pragma unroll
            for (int i = 0; i < 4; ++i)
                #pragma unroll
                for (int j = 0; j < 4; ++j)
                    acc[i][j] = __builtin_amdgcn_mfma_f32_16x16x32_bf16(af[i], bfr[j], acc[i][j], 0, 0, 0);
        }
    }

    // epilogue: bias + relu + per-cluster LDS accumulation ([col][k] layout)
    float b1v[4];
    #pragma unroll
    for (int j = 0; j < 4; ++j) b1v[j] = b1[wave * 64 + j * 16 + l15];

    #pragma unroll
    for (int i = 0; i < 4; ++i) {
        #pragma unroll
        for (int j = 0; j < 4; ++j) {
            const int col = wave * 64 + j * 16 + l15;
            #pragma unroll
            for (int r = 0; r < 4; ++r) {
                float v = fmaxf(acc[i][j][r] + b1v[j], 0.0f);
                int m = i * 16 + q * 4 + r;
                atomicAdd(&lsums[col * NC + cids[m]], v);
            }
        }
    }
    __syncthreads();
    #pragma unroll
    for (int k = 0; k < NC; ++k)
        atomicAdd(&gsums[tid * NC + k], lsums[tid * NC + k]);
}

// ---- Kernel 3: fused head: mean -> Linear+ReLU -> gated attn -> softmax ---
__global__ __launch_bounds__(256) void head_kernel(
    const float* __restrict__ gsums, const int* __restrict__ counts,
    const float* __restrict__ Wf, const float* __restrict__ bf1,
    const float* __restrict__ Wa, const float* __restrict__ ba,
    const float* __restrict__ Wb, const float* __restrict__ bb,
    const float* __restrict__ Wc, const float* __restrict__ bc,
    float* __restrict__ out)
{
    __shared__ float hcT[HDIM * NC];  // [d][k]
    __shared__ float hpT[HDIM * NC];  // [d][k]
    __shared__ float red[NC * 4];
    const int c = threadIdx.x;
    const int wave = c >> 6, lane = c & 63;

    #pragma unroll
    for (int k = 0; k < NC; ++k) {
        float inv = 1.0f / fmaxf((float)counts[k], 1.0f);
        hcT[c * NC + k] = gsums[c * NC + k] * inv;
    }
    __syncthreads();

    // h_path[k][c] = relu(Wf[c,:] . hc[k,:] + bf[c])
    {
        float acc[NC];
        float bias = bf1[c];
        #pragma unroll
        for (int k = 0; k < NC; ++k) acc[k] = bias;
        const float4* wf4 = (const float4*)(Wf + (size_t)c * HDIM);
        for (int d4 = 0; d4 < 64; ++d4) {
            float4 w = wf4[d4];
            #pragma unroll
            for (int e = 0; e < 4; ++e) {
                float wd = (e == 0) ? w.x : (e == 1) ? w.y : (e == 2) ? w.z : w.w;
                const f32x4 h0 = *(const f32x4*)&hcT[(d4 * 4 + e) * NC];
                const f32x4 h1 = *(const f32x4*)&hcT[(d4 * 4 + e) * NC + 4];
                acc[0] += wd * h0[0]; acc[1] += wd * h0[1];
                acc[2] += wd * h0[2]; acc[3] += wd * h0[3];
                acc[4] += wd * h1[0]; acc[5] += wd * h1[1];
                acc[6] += wd * h1[2]; acc[7] += wd * h1[3];
            }
        }
        #pragma unroll
        for (int k = 0; k < NC; ++k) hpT[c * NC + k] = fmaxf(acc[k], 0.0f);
    }
    __syncthreads();

    // gated attention logits
    float za[NC], zb[NC];
    {
        float biasa = ba[c], biasb = bb[c];
        #pragma unroll
        for (int k = 0; k < NC; ++k) { za[k] = biasa; zb[k] = biasb; }
        const float4* wa4 = (const float4*)(Wa + (size_t)c * HDIM);
        const float4* wb4 = (const float4*)(Wb + (size_t)c * HDIM);
        for (int d4 = 0; d4 < 64; ++d4) {
            float4 wa = wa4[d4], wb = wb4[d4];
            #pragma unroll
            for (int e = 0; e < 4; ++e) {
                float wav = (e == 0) ? wa.x : (e == 1) ? wa.y : (e == 2) ? wa.z : wa.w;
                float wbv = (e == 0) ? wb.x : (e == 1) ? wb.y : (e == 2) ? wb.z : wb.w;
                const f32x4 h0 = *(const f32x4*)&hpT[(d4 * 4 + e) * NC];
                const f32x4 h1 = *(const f32x4*)&hpT[(d4 * 4 + e) * NC + 4];
                za[0] += wav * h0[0]; za[1] += wav * h0[1]; za[2] += wav * h0[2]; za[3] += wav * h0[3];
                za[4] += wav * h1[0]; za[5] += wav * h1[1]; za[6] += wav * h1[2]; za[7] += wav * h1[3];
                zb[0] += wbv * h0[0]; zb[1] += wbv * h0[1]; zb[2] += wbv * h0[2]; zb[3] += wbv * h0[3];
                zb[4] += wbv * h1[0]; zb[5] += wbv * h1[1]; zb[6] += wbv * h1[2]; zb[7] += wbv * h1[3];
            }
        }
    }
    float wcv = Wc[c];
    float v[NC];
    #pragma unroll
    for (int k = 0; k < NC; ++k) {
        float a = tanhf(za[k]);
        float g = 1.0f / (1.0f + expf(-zb[k]));
        v[k] = a * g * wcv;
    }
    #pragma unroll
    for (int k = 0; k < NC; ++k) {
        float s = v[k];
        #pragma unroll
        for (int off = 32; off > 0; off >>= 1) s += __shfl_down(s, off, 64);
        if (lane == 0) red[k * 4 + wave] = s;
    }
    __syncthreads();
    float logit[NC], m = -1e30f;
    #pragma unroll
    for (int k = 0; k < NC; ++k) {
        logit[k] = red[k * 4] + red[k * 4 + 1] + red[k * 4 + 2] + red[k * 4 + 3] + bc[0];
        m = fmaxf(m, logit[k]);
    }
    float s = 0.0f, ex[NC];
    #pragma unroll
    for (int k = 0; k < NC; ++k) { ex[k] = expf(logit[k] - m); s += ex[k]; }
    float inv = 1.0f / s;
    float o = 0.0f;
    #pragma unroll
    for (int k = 0; k < NC; ++k) o += ex[k] * inv * hpT[c * NC + k];
    out[c] = o;
}

extern "C" void kernel_launch(void* const* d_in, const int* in_sizes, int n_in,
                              void* d_out, int out_size, void* d_ws, size_t ws_size,
                              hipStream_t stream)
{
    (void)in_sizes; (void)n_in; (void)out_size; (void)ws_size;
    const float* x   = (const float*)d_in[0];
    const int*   cid = (const int*)  d_in[1];
    const float* W1  = (const float*)d_in[2];
    const float* b1  = (const float*)d_in[3];
    const float* Wf  = (const float*)d_in[4];
    const float* bfv = (const float*)d_in[5];
    const float* Wa  = (const float*)d_in[6];
    const float* ba  = (const float*)d_in[7];
    const float* Wb  = (const float*)d_in[8];
    const float* bb  = (const float*)d_in[9];
    const float* Wc  = (const float*)d_in[10];
    const float* bc  = (const float*)d_in[11];
    float* out = (float*)d_out;

    // workspace layout
    unsigned short* W1b = (unsigned short*)d_ws;               // 262144 bf16 = 512 KB
    float* gsums  = (float*)((char*)d_ws + 524288);            // 2048 f32, [col][k]
    int*   counts = (int*)((char*)d_ws + 524288 + 8192);       // 8 ints

    hipMemsetAsync((char*)d_ws + 524288, 0, 8192 + 64, stream);

    hipLaunchKernelGGL(prep_kernel, dim3(128),  dim3(256), 0, stream, W1, W1b, cid, counts);
    hipLaunchKernelGGL(gemm_kernel, dim3(NN / BM), dim3(256), 0, stream, x, cid, W1b, b1, gsums);
    hipLaunchKernelGGL(head_kernel, dim3(1),    dim3(256), 0, stream,
                       gsums, counts, Wf, bfv, Wa, ba, Wb, bb, Wc, bc, out);
}

// Round 3
// 534.291 us; speedup vs baseline: 1.3174x; 1.2274x over previous
//
#include <hip/hip_runtime.h>
#include <hip/hip_bf16.h>

#define NN    65536
#define KDIM  1024
#define HDIM  256
#define NC    8
#define BM    64
#define NKB   16      // number of 64-wide K blocks

typedef __bf16 bf16x8 __attribute__((ext_vector_type(8)));
typedef float  f32x4  __attribute__((ext_vector_type(4)));
typedef __attribute__((address_space(1))) void GV;
typedef __attribute__((address_space(3))) void LV;

static __device__ __forceinline__ void async_cp16(const void* g, void* l) {
    __builtin_amdgcn_global_load_lds((GV*)g, (LV*)l, 16, 0, 0);
}

static __device__ __forceinline__ unsigned short f2bf_rne(float f) {
    unsigned int u = __float_as_uint(f);
    unsigned int r = u + 0x7fffu + ((u >> 16) & 1u);
    return (unsigned short)(r >> 16);
}

static __device__ __forceinline__ unsigned long long pack4bf(float4 v) {
    return (unsigned long long)f2bf_rne(v.x)
         | ((unsigned long long)f2bf_rne(v.y) << 16)
         | ((unsigned long long)f2bf_rne(v.z) << 32)
         | ((unsigned long long)f2bf_rne(v.w) << 48);
}

// ---- Kernel 1: W1 fp32 -> bf16 in gemm-tile order, + per-block cid hist ---
// W1b flat chunk index: kbi*2048 + h*1024 + n*4 + kc  (chunk = 8 bf16 = 16 B)
__global__ __launch_bounds__(256) void prep_kernel(
    const float* __restrict__ W1, unsigned short* __restrict__ W1b,
    const int* __restrict__ cid, int* __restrict__ cnt_partial)
{
    __shared__ int hcnt[NC];
    if (threadIdx.x < NC) hcnt[threadIdx.x] = 0;
    __syncthreads();

    const int gid = blockIdx.x * 256 + threadIdx.x;   // 0..32767
    const int kc  = gid & 3;
    const int n   = (gid >> 2) & 255;
    const int h   = (gid >> 10) & 1;
    const int kbi = gid >> 11;
    const float* src = W1 + (size_t)n * KDIM + kbi * 64 + h * 32 + kc * 8;
    float4 v0 = *(const float4*)(src);
    float4 v1 = *(const float4*)(src + 4);
    ulonglong2 pk;
    pk.x = pack4bf(v0);
    pk.y = pack4bf(v1);
    *(ulonglong2*)(W1b + (size_t)gid * 8) = pk;

    atomicAdd(&hcnt[cid[gid]], 1);                   // LDS atomics only
    atomicAdd(&hcnt[cid[gid + 32768]], 1);
    __syncthreads();
    if (threadIdx.x < NC)
        cnt_partial[blockIdx.x * NC + threadIdx.x] = hcnt[threadIdx.x];  // plain store
}

// ---- Kernel 2: bf16 MFMA GEMM + ReLU + per-cluster per-block segment sum --
__global__ __launch_bounds__(256, 3) void gemm_kernel(
    const float* __restrict__ x, const int* __restrict__ cid,
    const unsigned short* __restrict__ W1b, const float* __restrict__ b1,
    float* __restrict__ partial)
{
    __shared__ __align__(16) unsigned short xs[2][BM * 32];     // 8 KB
    __shared__ __align__(16) unsigned short wsb[2][HDIM * 32];  // 32 KB
    __shared__ float lsums[HDIM * NC];                          // 8 KB, [col][k]
    __shared__ int cids[BM];

    const int tid  = threadIdx.x;
    const int wave = tid >> 6;
    const int lane = tid & 63;
    const int l15  = lane & 15;
    const int q    = lane >> 4;
    const int row0 = blockIdx.x * BM;

    for (int i = tid; i < HDIM * NC; i += 256) lsums[i] = 0.0f;
    if (tid < BM) cids[tid] = cid[row0 + tid];

    f32x4 acc[4][4];
    #pragma unroll
    for (int i = 0; i < 4; ++i)
        #pragma unroll
        for (int j = 0; j < 4; ++j)
            #pragma unroll
            for (int r = 0; r < 4; ++r) acc[i][j][r] = 0.0f;

    // async W1 staging: wave covers chunks [wave*512, wave*512+512)
    const unsigned short* wg0 = W1b + ((size_t)(wave * 512 + lane)) * 8;
    unsigned short* wl0 = &wsb[0][0] + wave * 4096;

    // x: thread owns column chunk c = tid&15, rows p*16 + (tid>>4)
    const int xr = tid >> 4, xc = tid & 15;
    const float* xg = x + (size_t)(row0 + xr) * KDIM + xc * 4;

    float4 nx[4];
    #pragma unroll
    for (int p = 0; p < 4; ++p)
        nx[p] = *(const float4*)(xg + (size_t)p * 16 * KDIM);   // kbi = 0

    for (int kbi = 0; kbi < NKB; ++kbi) {
        __syncthreads();

        // write staged x (bf16) from registers
        #pragma unroll
        for (int p = 0; p < 4; ++p) {
            unsigned long long pk = pack4bf(nx[p]);
            int r = p * 16 + xr;
            *(unsigned long long*)&xs[xc >> 3][r * 32 + (xc & 7) * 4] = pk;
        }
        // async W1 tile (2048 chunks, lane-linear)
        const unsigned short* wg = wg0 + (size_t)kbi * 16384;
        #pragma unroll
        for (int t = 0; t < 8; ++t)
            async_cp16(wg + t * 512, wl0 + t * 512);

        __syncthreads();   // drains async W1 + x ds_writes

        // prefetch next x tile into registers (hides HBM latency under MFMA)
        if (kbi < NKB - 1) {
            #pragma unroll
            for (int p = 0; p < 4; ++p)
                nx[p] = *(const float4*)(xg + (kbi + 1) * 64 + (size_t)p * 16 * KDIM);
        }

        #pragma unroll
        for (int s = 0; s < 2; ++s) {
            bf16x8 af[4], bfr[4];
            #pragma unroll
            for (int i = 0; i < 4; ++i)
                af[i] = *(const bf16x8*)&xs[s][(i * 16 + l15) * 32 + q * 8];
            #pragma unroll
            for (int j = 0; j < 4; ++j)
                bfr[j] = *(const bf16x8*)&wsb[s][(wave * 64 + j * 16 + l15) * 32 + q * 8];
            #pragma unroll
            for (int i = 0; i < 4; ++i)
                #pragma unroll
                for (int j = 0; j < 4; ++j)
                    acc[i][j] = __builtin_amdgcn_mfma_f32_16x16x32_bf16(af[i], bfr[j], acc[i][j], 0, 0, 0);
        }
    }

    // epilogue: bias + relu + per-cluster LDS accumulation ([col][k] layout)
    float b1v[4];
    #pragma unroll
    for (int j = 0; j < 4; ++j) b1v[j] = b1[wave * 64 + j * 16 + l15];

    #pragma unroll
    for (int i = 0; i < 4; ++i) {
        #pragma unroll
        for (int j = 0; j < 4; ++j) {
            const int col = wave * 64 + j * 16 + l15;
            #pragma unroll
            for (int r = 0; r < 4; ++r) {
                float v = fmaxf(acc[i][j][r] + b1v[j], 0.0f);
                int m = i * 16 + q * 4 + r;
                atomicAdd(&lsums[col * NC + cids[m]], v);
            }
        }
    }
    __syncthreads();
    // plain coalesced store of this block's partial sums (NO global atomics)
    float* dst = partial + (size_t)blockIdx.x * 2048 + tid * 8;
    *(f32x4*)dst       = *(const f32x4*)&lsums[tid * 8];
    *(f32x4*)(dst + 4) = *(const f32x4*)&lsums[tid * 8 + 4];
}

// ---- Kernel 3: reduce 1024 partials -> stage2[8][2048] (no atomics) -------
__global__ __launch_bounds__(256) void reduce_kernel(
    const float* __restrict__ partial, float* __restrict__ stage2)
{
    const int s  = blockIdx.x >> 3;   // pb-split 0..7 (128 blocks each)
    const int og = blockIdx.x & 7;    // output group
    const int o  = og * 256 + threadIdx.x;
    const float* p = partial + (size_t)s * 128 * 2048 + o;
    float a0=0,a1=0,a2=0,a3=0,a4=0,a5=0,a6=0,a7=0;
    #pragma unroll 4
    for (int pb = 0; pb < 128; pb += 8) {
        a0 += p[(size_t)(pb+0)*2048]; a1 += p[(size_t)(pb+1)*2048];
        a2 += p[(size_t)(pb+2)*2048]; a3 += p[(size_t)(pb+3)*2048];
        a4 += p[(size_t)(pb+4)*2048]; a5 += p[(size_t)(pb+5)*2048];
        a6 += p[(size_t)(pb+6)*2048]; a7 += p[(size_t)(pb+7)*2048];
    }
    stage2[(size_t)s * 2048 + o] = ((a0+a1)+(a2+a3)) + ((a4+a5)+(a6+a7));
}

// ---- Kernel 4: fused head: counts+mean -> Linear+ReLU -> gated attn -------
__global__ __launch_bounds__(256) void head_kernel(
    const float* __restrict__ stage2, const int* __restrict__ cnt_partial,
    const float* __restrict__ Wf, const float* __restrict__ bf1,
    const float* __restrict__ Wa, const float* __restrict__ ba,
    const float* __restrict__ Wb, const float* __restrict__ bb,
    const float* __restrict__ Wc, const float* __restrict__ bc,
    float* __restrict__ out)
{
    __shared__ float hcT[HDIM * NC];  // [d][k]
    __shared__ float hpT[HDIM * NC];  // [d][k]
    __shared__ float red[NC * 4];
    __shared__ int   cnt_s[256];
    __shared__ float cnt_f[NC];
    const int c = threadIdx.x;
    const int wave = c >> 6, lane = c & 63;

    // reduce counts: 128 blocks x 8 -> 8
    {
        int k = c & 7, g = c >> 3;                     // g 0..31
        const int* cp = cnt_partial + g * 32 + k;      // 4 blocks of 8
        cnt_s[c] = cp[0] + cp[8] + cp[16] + cp[24];
    }
    __syncthreads();
    if (c < NC) {
        int s = 0;
        #pragma unroll
        for (int g = 0; g < 32; ++g) s += cnt_s[g * 8 + c];
        cnt_f[c] = 1.0f / fmaxf((float)s, 1.0f);
    }
    __syncthreads();

    // final gsum reduce (8 stage2 slices) + mean
    {
        float a[NC] = {0,0,0,0,0,0,0,0};
        #pragma unroll
        for (int s = 0; s < 8; ++s) {
            f32x4 u0 = *(const f32x4*)&stage2[(size_t)s * 2048 + c * 8];
            f32x4 u1 = *(const f32x4*)&stage2[(size_t)s * 2048 + c * 8 + 4];
            a[0]+=u0[0]; a[1]+=u0[1]; a[2]+=u0[2]; a[3]+=u0[3];
            a[4]+=u1[0]; a[5]+=u1[1]; a[6]+=u1[2]; a[7]+=u1[3];
        }
        #pragma unroll
        for (int k = 0; k < NC; ++k) hcT[c * NC + k] = a[k] * cnt_f[k];
    }
    __syncthreads();

    // h_path[k][c] = relu(Wf[c,:] . hc[k,:] + bf[c])
    {
        float acc[NC];
        float bias = bf1[c];
        #pragma unroll
        for (int k = 0; k < NC; ++k) acc[k] = bias;
        const float4* wf4 = (const float4*)(Wf + (size_t)c * HDIM);
        for (int d4 = 0; d4 < 64; ++d4) {
            float4 w = wf4[d4];
            #pragma unroll
            for (int e = 0; e < 4; ++e) {
                float wd = (e == 0) ? w.x : (e == 1) ? w.y : (e == 2) ? w.z : w.w;
                const f32x4 h0 = *(const f32x4*)&hcT[(d4 * 4 + e) * NC];
                const f32x4 h1 = *(const f32x4*)&hcT[(d4 * 4 + e) * NC + 4];
                acc[0] += wd * h0[0]; acc[1] += wd * h0[1];
                acc[2] += wd * h0[2]; acc[3] += wd * h0[3];
                acc[4] += wd * h1[0]; acc[5] += wd * h1[1];
                acc[6] += wd * h1[2]; acc[7] += wd * h1[3];
            }
        }
        #pragma unroll
        for (int k = 0; k < NC; ++k) hpT[c * NC + k] = fmaxf(acc[k], 0.0f);
    }
    __syncthreads();

    // gated attention logits
    float za[NC], zb[NC];
    {
        float biasa = ba[c], biasb = bb[c];
        #pragma unroll
        for (int k = 0; k < NC; ++k) { za[k] = biasa; zb[k] = biasb; }
        const float4* wa4 = (const float4*)(Wa + (size_t)c * HDIM);
        const float4* wb4 = (const float4*)(Wb + (size_t)c * HDIM);
        for (int d4 = 0; d4 < 64; ++d4) {
            float4 wa = wa4[d4], wb = wb4[d4];
            #pragma unroll
            for (int e = 0; e < 4; ++e) {
                float wav = (e == 0) ? wa.x : (e == 1) ? wa.y : (e == 2) ? wa.z : wa.w;
                float wbv = (e == 0) ? wb.x : (e == 1) ? wb.y : (e == 2) ? wb.z : wb.w;
                const f32x4 h0 = *(const f32x4*)&hpT[(d4 * 4 + e) * NC];
                const f32x4 h1 = *(const f32x4*)&hpT[(d4 * 4 + e) * NC + 4];
                za[0] += wav * h0[0]; za[1] += wav * h0[1]; za[2] += wav * h0[2]; za[3] += wav * h0[3];
                za[4] += wav * h1[0]; za[5] += wav * h1[1]; za[6] += wav * h1[2]; za[7] += wav * h1[3];
                zb[0] += wbv * h0[0]; zb[1] += wbv * h0[1]; zb[2] += wbv * h0[2]; zb[3] += wbv * h0[3];
                zb[4] += wbv * h1[0]; zb[5] += wbv * h1[1]; zb[6] += wbv * h1[2]; zb[7] += wbv * h1[3];
            }
        }
    }
    float wcv = Wc[c];
    float v[NC];
    #pragma unroll
    for (int k = 0; k < NC; ++k) {
        float a = tanhf(za[k]);
        float g = 1.0f / (1.0f + expf(-zb[k]));
        v[k] = a * g * wcv;
    }
    #pragma unroll
    for (int k = 0; k < NC; ++k) {
        float s = v[k];
        #pragma unroll
        for (int off = 32; off > 0; off >>= 1) s += __shfl_down(s, off, 64);
        if (lane == 0) red[k * 4 + wave] = s;
    }
    __syncthreads();
    float logit[NC], m = -1e30f;
    #pragma unroll
    for (int k = 0; k < NC; ++k) {
        logit[k] = red[k * 4] + red[k * 4 + 1] + red[k * 4 + 2] + red[k * 4 + 3] + bc[0];
        m = fmaxf(m, logit[k]);
    }
    float s = 0.0f, ex[NC];
    #pragma unroll
    for (int k = 0; k < NC; ++k) { ex[k] = expf(logit[k] - m); s += ex[k]; }
    float inv = 1.0f / s;
    float o = 0.0f;
    #pragma unroll
    for (int k = 0; k < NC; ++k) o += ex[k] * inv * hpT[c * NC + k];
    out[c] = o;
}

extern "C" void kernel_launch(void* const* d_in, const int* in_sizes, int n_in,
                              void* d_out, int out_size, void* d_ws, size_t ws_size,
                              hipStream_t stream)
{
    (void)in_sizes; (void)n_in; (void)out_size; (void)ws_size;
    const float* x   = (const float*)d_in[0];
    const int*   cid = (const int*)  d_in[1];
    const float* W1  = (const float*)d_in[2];
    const float* b1  = (const float*)d_in[3];
    const float* Wf  = (const float*)d_in[4];
    const float* bfv = (const float*)d_in[5];
    const float* Wa  = (const float*)d_in[6];
    const float* ba  = (const float*)d_in[7];
    const float* Wb  = (const float*)d_in[8];
    const float* bb  = (const float*)d_in[9];
    const float* Wc  = (const float*)d_in[10];
    const float* bc  = (const float*)d_in[11];
    float* out = (float*)d_out;

    // workspace layout (~9.0 MB, no zero-init required anywhere)
    unsigned short* W1b   = (unsigned short*)d_ws;                     // 512 KB
    int*   cnt_partial    = (int*)  ((char*)d_ws + 524288);            // 4 KB
    float* partial        = (float*)((char*)d_ws + 528384);            // 8 MB
    float* stage2         = (float*)((char*)d_ws + 528384 + 8388608);  // 64 KB

    hipLaunchKernelGGL(prep_kernel,   dim3(128),     dim3(256), 0, stream, W1, W1b, cid, cnt_partial);
    hipLaunchKernelGGL(gemm_kernel,   dim3(NN / BM), dim3(256), 0, stream, x, cid, W1b, b1, partial);
    hipLaunchKernelGGL(reduce_kernel, dim3(64),      dim3(256), 0, stream, partial, stage2);
    hipLaunchKernelGGL(head_kernel,   dim3(1),       dim3(256), 0, stream,
                       stage2, cnt_partial, Wf, bfv, Wa, ba, Wb, bb, Wc, bc, out);
}